// Round 5
// baseline (348.373 us; speedup 1.0000x reference)
//
#include <hip/hip_runtime.h>
#include <math.h>

#define Nn 8192
#define Dd 256
#define Cc 16

// ---- workspace layout (floats) ----
#define OFF_P0   0u          // 8192*256: MX -> gemm1 partial0 -> gemm2 partials
#define OFF_P1   2097152u    // 8192*256: gemm1 partial1
#define OFF_G    4194304u    // bf16[8192*256]; later logits f32 (131072 floats)
#define OFF_GT   5242880u    // bf16[256*8192] transposed
#define OFF_G1B  6291456u    // bf16[8192] (gamma-1)
#define OFF_DEN  6295552u    // 2*8192 f32 (split partials)
#define OFF_RS   6311936u    // 2*8192 f32
#define OFF_KC   6328320u    // 64
#define WS_FLOATS 6328384u

typedef short vshort8 __attribute__((ext_vector_type(8)));
typedef float vfloat4 __attribute__((ext_vector_type(4)));

__device__ __forceinline__ float clip1(float x) {
    return fminf(fmaxf(x, -1.0f + 1e-7f), 1.0f - 1e-7f);
}

__device__ __forceinline__ unsigned short f2bf(float f) {
    unsigned int u = __float_as_uint(f);
    u += 0x7fff + ((u >> 16) & 1);          // round-to-nearest-even
    return (unsigned short)(u >> 16);
}

__device__ __forceinline__ float waveReduce(float v) {
    #pragma unroll
    for (int off = 32; off; off >>= 1) v += __shfl_down(v, off);
    return v;
}

__device__ __forceinline__ float blockReduceBcast(float v, float* red) {
    int t = threadIdx.x, w = t >> 6, l = t & 63;
    v = waveReduce(v);
    if (l == 0) red[w] = v;
    __syncthreads();
    if (t == 0) red[0] = red[0] + red[1] + red[2] + red[3];
    __syncthreads();
    float r = red[0];
    __syncthreads();
    return r;
}

// ---- K0: per-prototype constants ----
__global__ __launch_bounds__(256) void k_consts(const float* __restrict__ Wl,
                                                const float* __restrict__ Pk,
                                                float* __restrict__ kc) {
    __shared__ float red[8];
    int t = threadIdx.x, k = blockIdx.x;
    float pv = Pk[k * Dd + t];
    float wv = Wl[t * Cc + k];
    float p2 = blockReduceBcast(pv * pv, red);
    float pw = blockReduceBcast(pv * wv, red);
    float w2 = blockReduceBcast(wv * wv, red);
    if (t == 0) {
        float an  = fmaxf(sqrtf(w2), 1e-15f);
        float lam = 2.0f / fmaxf(1.0f - p2, 1e-10f);
        kc[k * 4 + 0] = p2; kc[k * 4 + 1] = pw;
        kc[k * 4 + 2] = an; kc[k * 4 + 3] = lam;
    }
}

// ---- K1a: MX = X @ W^T (fp32 VALU; small) ----
__global__ __launch_bounds__(256) void k_xwt(const float* __restrict__ X,
                                             const float* __restrict__ W,
                                             float* __restrict__ MX) {
    __shared__ __align__(16) float Xs[32 * 68];
    __shared__ __align__(16) float Ws[32 * 260];
    int t = threadIdx.x;
    int m0 = blockIdx.x * 64;
    int tx = t & 15, ty = t >> 4;
    float acc[4][16] = {};
    for (int k0 = 0; k0 < Dd; k0 += 32) {
        #pragma unroll
        for (int i = 0; i < 2; ++i) {
            int idx = t + i * 256;
            int row = idx >> 3, kq = idx & 7;
            float4 v = *(const float4*)&X[(size_t)(m0 + row) * Dd + k0 + kq * 4];
            Xs[(kq * 4 + 0) * 68 + row] = v.x;
            Xs[(kq * 4 + 1) * 68 + row] = v.y;
            Xs[(kq * 4 + 2) * 68 + row] = v.z;
            Xs[(kq * 4 + 3) * 68 + row] = v.w;
        }
        #pragma unroll
        for (int i = 0; i < 8; ++i) {
            int n = (t >> 3) + i * 32;
            int kq = t & 7;
            float4 v = *(const float4*)&W[(size_t)n * Dd + k0 + kq * 4];
            Ws[(kq * 4 + 0) * 260 + n] = v.x;
            Ws[(kq * 4 + 1) * 260 + n] = v.y;
            Ws[(kq * 4 + 2) * 260 + n] = v.z;
            Ws[(kq * 4 + 3) * 260 + n] = v.w;
        }
        __syncthreads();
        #pragma unroll
        for (int k = 0; k < 32; ++k) {
            float4 a = *(const float4*)&Xs[k * 68 + ty * 4];
            float av[4] = {a.x, a.y, a.z, a.w};
            #pragma unroll
            for (int q = 0; q < 4; ++q) {
                float4 b = *(const float4*)&Ws[k * 260 + q * 64 + tx * 4];
                float bv[4] = {b.x, b.y, b.z, b.w};
                #pragma unroll
                for (int i2 = 0; i2 < 4; ++i2)
                    #pragma unroll
                    for (int j = 0; j < 4; ++j)
                        acc[i2][q * 4 + j] += av[i2] * bv[j];
            }
        }
        __syncthreads();
    }
    #pragma unroll
    for (int i2 = 0; i2 < 4; ++i2)
        #pragma unroll
        for (int q = 0; q < 4; ++q) {
            float4 v = make_float4(acc[i2][q * 4 + 0], acc[i2][q * 4 + 1],
                                   acc[i2][q * 4 + 2], acc[i2][q * 4 + 3]);
            *(float4*)&MX[(size_t)(m0 + ty * 4 + i2) * Dd + q * 64 + tx * 4] = v;
        }
}

// ---- K1b: per-row mobius_matvec rescale + gamma; G bf16, g1 bf16 ----
__global__ __launch_bounds__(256) void k_gamma(const float* __restrict__ X,
                                               const float* __restrict__ MX,
                                               unsigned short* __restrict__ G,
                                               unsigned short* __restrict__ g1b) {
    __shared__ float red[8];
    int i = blockIdx.x, t = threadIdx.x;
    float x  = X[(size_t)i * Dd + t];
    float mx = MX[(size_t)i * Dd + t];
    float xn2  = blockReduceBcast(x * x, red);
    float mxn2 = blockReduceBcast(mx * mx, red);
    float xn  = fmaxf(sqrtf(xn2), 1e-15f);
    float mxn = fmaxf(sqrtf(mxn2), 1e-15f);
    float s = tanhf(mxn / xn * atanhf(clip1(xn))) / mxn;
    float xw = s * mx;
    float xw2 = blockReduceBcast(xw * xw, red);
    float gamma = 2.0f / fmaxf(1.0f - xw2, 1e-10f);
    G[(size_t)i * Dd + t] = f2bf(gamma * xw);
    if (t == 0) g1b[i] = f2bf(gamma - 1.0f);
}

// ---- K1c: Gt = transpose(G)  (bf16, 64x64 LDS tiles) ----
__global__ __launch_bounds__(256) void k_tr(const unsigned short* __restrict__ G,
                                            unsigned short* __restrict__ Gt) {
    __shared__ unsigned short Ts[64 * 66];
    int t = threadIdx.x;
    int i0 = blockIdx.x * 64;
    int j0 = blockIdx.y * 64;
    {
        int r = t >> 2, cq = t & 3;
        const uint4* src = (const uint4*)&G[(size_t)(i0 + r) * Dd + j0 + cq * 16];
        uint4 v0 = src[0], v1 = src[1];
        *(uint4*)&Ts[r * 66 + cq * 16]     = v0;
        *(uint4*)&Ts[r * 66 + cq * 16 + 8] = v1;
    }
    __syncthreads();
    {
        int c = t >> 2, rq = t & 3;
        unsigned short v[16];
        #pragma unroll
        for (int e = 0; e < 16; ++e) v[e] = Ts[(rq * 16 + e) * 66 + c];
        uint4 o0, o1;
        unsigned int* o = (unsigned int*)&o0;
        #pragma unroll
        for (int q = 0; q < 4; ++q)
            o[q] = (unsigned int)v[q * 2] | ((unsigned int)v[q * 2 + 1] << 16);
        o = (unsigned int*)&o1;
        #pragma unroll
        for (int q = 0; q < 4; ++q)
            o[q] = (unsigned int)v[8 + q * 2] | ((unsigned int)v[8 + q * 2 + 1] << 16);
        uint4* dst = (uint4*)&Gt[(size_t)(j0 + c) * Nn + i0 + rq * 16];
        dst[0] = o0; dst[1] = o1;
    }
}

// ======== K2 helpers ========
__device__ __forceinline__ void load_bfrags(const unsigned short* const (&gtb)[4],
                                            int tc, vshort8 (&bf)[8]) {
    #pragma unroll
    for (int ni = 0; ni < 4; ++ni)
        #pragma unroll
        for (int kk = 0; kk < 2; ++kk)
            bf[ni * 2 + kk] = *(const vshort8*)(gtb[ni] + tc * 64 + kk * 32);
}

__device__ __forceinline__ void load_arow(const float* __restrict__ Abase,
                                          int tc, float (&a8)[8]) {
    const vfloat4* p = (const vfloat4*)(Abase + tc * 64);
    *(vfloat4*)&a8[0] = __builtin_nontemporal_load(p);
    *(vfloat4*)&a8[4] = __builtin_nontemporal_load(p + 1);
}

__device__ __forceinline__ void cvt_fold(unsigned short (&Asb)[32][64],
        const unsigned short* g1s, const float (&ab)[8],
        int tile, int ar, int aq, float& dacc, float& racc) {
    vshort8 gv = *(const vshort8*)&g1s[tile * 64 + aq * 8];
    vshort8 o;
    #pragma unroll
    for (int e = 0; e < 8; ++e) {
        float av = ab[e];
        o[e] = (short)f2bf(av);
        float gf = __uint_as_float(((unsigned int)(unsigned short)gv[e]) << 16);
        dacc += av * gf;
        racc += av;
    }
    *(vshort8*)((char*)&Asb[ar][0] + ((aq * 16) ^ ((ar & 7) << 4))) = o;
}

__device__ __forceinline__ void phase_mfma(const unsigned short (&Asb)[32][64],
        const vshort8 (&bf)[8], int l, vfloat4 (&acc)[2][4]) {
    #pragma unroll
    for (int kk = 0; kk < 2; ++kk) {
        int ke2 = (kk * 32 + ((l >> 4) << 3)) * 2;
        vshort8 af[2];
        #pragma unroll
        for (int mi = 0; mi < 2; ++mi) {
            int row = mi * 16 + (l & 15);
            af[mi] = *(const vshort8*)((const char*)&Asb[row][0] + (ke2 ^ ((row & 7) << 4)));
        }
        #pragma unroll
        for (int mi = 0; mi < 2; ++mi)
            #pragma unroll
            for (int ni = 0; ni < 4; ++ni)
                acc[mi][ni] = __builtin_amdgcn_mfma_f32_16x16x32_bf16(
                    af[mi], bf[ni * 2 + kk], acc[mi][ni], 0, 0, 0);
    }
}

// ---- K2: P[split] = A(k-slice) @ G ----
// B fragments are wave-private -> global->VGPR direct (no LDS round-trip).
// Only A tile (cross-wave shared) goes through LDS (dbuf). One s_barrier +
// lgkmcnt(0) per phase; NO vmcnt drain (all vmem dests are registers).
__global__ __launch_bounds__(256, 2) void k_gemm1_mfma(
        const float* __restrict__ A,
        const unsigned short* __restrict__ Gt,
        const unsigned short* __restrict__ g1b,
        float* __restrict__ Ppart,
        float* __restrict__ denp,
        float* __restrict__ rsp) {
    __shared__ __align__(16) unsigned short As[2][32][64];   // 8 KB dbuf
    __shared__ __align__(16) unsigned short g1s[4096];       // 8 KB

    const int t = threadIdx.x;
    const int l = t & 63, w = t >> 6;
    const int id = blockIdx.x;
    const int splt = id & 1;                 // XCD (id%8) sees one split parity
    const int m0 = (id >> 1) * 32;
    const int kb = splt * 4096;

    const int ar = t >> 3, aq = t & 7;       // A staging: row, k-octet
    const int c0 = w * 64;                   // wave's private 64 B-cols

    const unsigned short* gtb[4];
    #pragma unroll
    for (int ni = 0; ni < 4; ++ni)
        gtb[ni] = &Gt[(size_t)(c0 + ni * 16 + (l & 15)) * Nn + kb + ((l >> 4) << 3)];
    const float* Abase = &A[(size_t)(m0 + ar) * Nn + kb + aq * 8];

    vfloat4 acc[2][4];
    #pragma unroll
    for (int mi = 0; mi < 2; ++mi)
        #pragma unroll
        for (int ni = 0; ni < 4; ++ni)
            acc[mi][ni] = (vfloat4){0.f, 0.f, 0.f, 0.f};
    float dacc = 0.f, racc = 0.f;

    vshort8 bf0[8], bf1[8];                  // B frag dbuf (tile parity)
    float a0[8], a1[8], a2[8], a3[8];        // raw A 4-deep pipeline

    // ---- prologue ----
    #pragma unroll
    for (int i = 0; i < 2; ++i) {
        int idx = i * 256 + t;
        *(uint4*)&g1s[idx * 8] = *(const uint4*)&g1b[kb + idx * 8];
    }
    load_bfrags(gtb, 0, bf0);
    load_arow(Abase, 0, a0);
    load_arow(Abase, 1, a1);
    load_arow(Abase, 2, a2);
    asm volatile("s_waitcnt lgkmcnt(0)" ::: "memory");
    __builtin_amdgcn_s_barrier();            // g1s visible
    cvt_fold(As[0], g1s, a0, 0, ar, aq, dacc, racc);
    asm volatile("s_waitcnt lgkmcnt(0)" ::: "memory");
    __builtin_amdgcn_s_barrier();            // As[0] visible

    // ---- main loop: 16 trips x 4 phases; all buffer indices compile-time ----
    for (int u = 0; u < 16; ++u) {
        #pragma unroll
        for (int pp = 0; pp < 4; ++pp) {
            const int p = u * 4 + pp;
            // 1. prefetch B frags for tile p+1 (distance 1, L2-resident)
            if (p < 63) {
                if (pp & 1) load_bfrags(gtb, p + 1, bf0);
                else        load_bfrags(gtb, p + 1, bf1);
            }
            // 2. prefetch raw A for tile p+3 (distance 2+)
            if (p < 61) {
                float (&adst)[8] = (pp == 0) ? a3 : (pp == 1) ? a0
                                 : (pp == 2) ? a1 : a2;
                load_arow(Abase, p + 3, adst);
            }
            // 3. compute tile p
            if (pp & 1) phase_mfma(As[1], bf1, l, acc);
            else        phase_mfma(As[0], bf0, l, acc);
            // 4. stage A tile p+1 into the other LDS buffer
            if (p < 63) {
                float (&asrc)[8] = (pp == 0) ? a1 : (pp == 1) ? a2
                                 : (pp == 2) ? a3 : a0;
                if (pp & 1) cvt_fold(As[0], g1s, asrc, p + 1, ar, aq, dacc, racc);
                else        cvt_fold(As[1], g1s, asrc, p + 1, ar, aq, dacc, racc);
            }
            // 5. publish
            asm volatile("s_waitcnt lgkmcnt(0)" ::: "memory");
            __builtin_amdgcn_s_barrier();
        }
    }

    // ---- den/rs: reduce across the 8 k-octet threads of each row ----
    dacc += __shfl_xor(dacc, 1); dacc += __shfl_xor(dacc, 2); dacc += __shfl_xor(dacc, 4);
    racc += __shfl_xor(racc, 1); racc += __shfl_xor(racc, 2); racc += __shfl_xor(racc, 4);
    if (aq == 0) {
        denp[splt * Nn + m0 + ar] = dacc;
        rsp[splt * Nn + m0 + ar] = racc;
    }

    // ---- store fp32 partial ----
    float* P = Ppart + (size_t)splt * ((size_t)Nn * Dd);
    #pragma unroll
    for (int mi = 0; mi < 2; ++mi)
        #pragma unroll
        for (int ni = 0; ni < 4; ++ni) {
            int row = m0 + mi * 16 + ((l >> 4) << 2);
            int col = c0 + ni * 16 + (l & 15);
            #pragma unroll
            for (int j = 0; j < 4; ++j)
                P[(size_t)(row + j) * Dd + col] = acc[mi][ni][j];
        }
}

// ---- K3: per-row gyromidpoint chain + H1 + hyperbolic logits ----
__global__ __launch_bounds__(256) void k_rowfix(const float* __restrict__ P0,
                                                const float* __restrict__ P1,
                                                const float* __restrict__ denp,
                                                const float* __restrict__ rsp,
                                                const float* __restrict__ Pk,
                                                const float* __restrict__ Wl,
                                                const float* __restrict__ kc,
                                                float* __restrict__ logits) {
    __shared__ float red[8];
    __shared__ float hs[256];
    __shared__ float PQ[16][2];
    int i = blockIdx.x, t = threadIdx.x;
    float nom = P0[(size_t)i * Dd + t] + P1[(size_t)i * Dd + t];
    float dv = denp[i] + denp[Nn + i];
    dv = (fabsf(dv) < 1e-10f) ? 1e-10f : dv;
    float tm = nom / dv;
    float r2 = blockReduceBcast(tm * tm, red);
    float r = fmaxf(sqrtf(r2), 1e-15f);
    float mmul = tanhf(0.5f * atanhf(clip1(r))) / r;
    float mj = mmul * tm;
    float mn2 = blockReduceBcast(mj * mj, red);
    float mn = fmaxf(sqrtf(mn2), 1e-15f);
    float sA = rsp[i] + rsp[Nn + i];
    float axmul = tanhf(sA * atanhf(clip1(mn))) / mn;
    float axw = axmul * mj;
    float yn2 = blockReduceBcast(axw * axw, red);
    float yn = fmaxf(sqrtf(yn2), 1e-15f);
    float v = atanhf(clip1(yn)) / yn * axw;
    float u = fmaxf(v, 0.0f);
    float un2 = blockReduceBcast(u * u, red);
    float un = fmaxf(sqrtf(un2), 1e-15f);
    float h = tanhf(un) / un * u;
    float h2 = blockReduceBcast(h * h, red);
    hs[t] = h;
    __syncthreads();
    int w = t >> 6, l = t & 63;
    #pragma unroll
    for (int kk = 0; kk < 4; ++kk) {
        int k = w * 4 + kk;
        float pp = 0.f, qq = 0.f;
        #pragma unroll
        for (int m = 0; m < 4; ++m) {
            float hv = hs[l + 64 * m];
            pp += hv * Pk[k * Dd + l + 64 * m];
            qq += hv * Wl[(l + 64 * m) * Cc + k];
        }
        pp = waveReduce(pp);
        qq = waveReduce(qq);
        if (l == 0) { PQ[k][0] = pp; PQ[k][1] = qq; }
    }
    __syncthreads();
    if (t < 16) {
        int k = t;
        float p2 = kc[k * 4 + 0], pw = kc[k * 4 + 1];
        float an = kc[k * 4 + 2], lam = kc[k * 4 + 3];
        float P = PQ[k][0], Q = PQ[k][1];
        float alpha = 1.0f - 2.0f * P + h2;
        float beta  = 1.0f - p2;
        float Dm = fmaxf(1.0f - 2.0f * P + p2 * h2, 1e-15f);
        float za  = (-alpha * pw + beta * Q) / Dm;
        float zn2 = (alpha * alpha * p2 - 2.0f * alpha * beta * P + beta * beta * h2)
                    / (Dm * Dm);
        float dd = fmaxf(1.0f - zn2, 1e-10f) * an;
        float dist = asinhf(2.0f * za / dd);
        logits[(size_t)i * Cc + k] = lam * an * dist;
    }
}

// ---- K4: partials of out = A @ logits (j-split x16) ----
__global__ __launch_bounds__(256) void k_gemm2(const float* __restrict__ A,
                                               const float* __restrict__ L,
                                               float* __restrict__ part) {
    __shared__ __align__(16) float Ls[64 * 20];
    __shared__ float Pacc[256 * 16];
    int t = threadIdx.x;
    int r0 = blockIdx.x * 256;
    int jbase = blockIdx.y * 512;
    int q = t & 3, g = t >> 2;
    float acc[4][16] = {};
    for (int jc = 0; jc < 512; jc += 64) {
        {
            int jrow = t >> 2, kq = t & 3;
            *(float4*)&Ls[jrow * 20 + kq * 4] =
                *(const float4*)&L[(size_t)(jbase + jc + jrow) * Cc + kq * 4];
        }
        __syncthreads();
        #pragma unroll
        for (int m = 0; m < 4; ++m) {
            int jl = m * 16 + q * 4;
            float av[4][4];
            #pragma unroll
            for (int rr = 0; rr < 4; ++rr) {
                vfloat4 tmp = __builtin_nontemporal_load(
                    (const vfloat4*)&A[(size_t)(r0 + g * 4 + rr) * Nn + jbase + jc + jl]);
                av[rr][0] = tmp[0]; av[rr][1] = tmp[1];
                av[rr][2] = tmp[2]; av[rr][3] = tmp[3];
            }
            #pragma unroll
            for (int jj = 0; jj < 4; ++jj) {
                const float* lr = &Ls[(jl + jj) * 20];
                float lv[16];
                #pragma unroll
                for (int k2 = 0; k2 < 16; k2 += 4) {
                    float4 lt = *(const float4*)&lr[k2];
                    lv[k2] = lt.x; lv[k2 + 1] = lt.y;
                    lv[k2 + 2] = lt.z; lv[k2 + 3] = lt.w;
                }
                #pragma unroll
                for (int rr = 0; rr < 4; ++rr)
                    #pragma unroll
                    for (int k2 = 0; k2 < 16; ++k2)
                        acc[rr][k2] += av[rr][jj] * lv[k2];
            }
        }
        __syncthreads();
    }
    for (int ii = t; ii < 4096; ii += 256) Pacc[ii] = 0.f;
    __syncthreads();
    for (int qq = 0; qq < 4; ++qq) {
        if (q == qq) {
            #pragma unroll
            for (int rr = 0; rr < 4; ++rr)
                #pragma unroll
                for (int k2 = 0; k2 < 16; ++k2)
                    Pacc[(g * 4 + rr) * 16 + k2] += acc[rr][k2];
        }
        __syncthreads();
    }
    float* dst = &part[(size_t)blockIdx.y * (Nn * Cc) + (size_t)r0 * Cc];
    for (int ii = t * 4; ii < 4096; ii += 1024)
        *(float4*)&dst[ii] = *(const float4*)&Pacc[ii];
}

// ---- K5: reduce j-split partials ----
__global__ __launch_bounds__(256) void k_reduce(const float* __restrict__ part,
                                                float* __restrict__ out) {
    int i = blockIdx.x * 256 + threadIdx.x;
    float s = 0.f;
    #pragma unroll
    for (int j = 0; j < 16; ++j) s += part[(size_t)j * (Nn * Cc) + i];
    out[i] = s;
}

extern "C" void kernel_launch(void* const* d_in, const int* in_sizes, int n_in,
                              void* d_out, int out_size, void* d_ws, size_t ws_size,
                              hipStream_t stream) {
    const float* X  = (const float*)d_in[0];
    const float* A  = (const float*)d_in[1];
    const float* W  = (const float*)d_in[2];
    const float* Wl = (const float*)d_in[3];
    const float* Pk = (const float*)d_in[4];
    float* out = (float*)d_out;
    float* ws = (float*)d_ws;
    if (ws_size < (size_t)WS_FLOATS * sizeof(float)) return;

    float* P0 = ws + OFF_P0;
    float* P1 = ws + OFF_P1;
    unsigned short* G   = (unsigned short*)(ws + OFF_G);
    unsigned short* Gt  = (unsigned short*)(ws + OFF_GT);
    unsigned short* g1b = (unsigned short*)(ws + OFF_G1B);
    float* lg   = ws + OFF_G;                      // logits reuse G region
    float* denp = ws + OFF_DEN;
    float* rsp  = ws + OFF_RS;
    float* kc   = ws + OFF_KC;

    k_consts<<<16, 256, 0, stream>>>(Wl, Pk, kc);
    k_xwt<<<128, 256, 0, stream>>>(X, W, P0 /*MX*/);
    k_gamma<<<Nn, 256, 0, stream>>>(X, P0 /*MX*/, G, g1b);
    k_tr<<<dim3(128, 4), 256, 0, stream>>>(G, Gt);
    k_gemm1_mfma<<<512, 256, 0, stream>>>(A, Gt, g1b, P0, denp, rsp);
    k_rowfix<<<Nn, 256, 0, stream>>>(P0, P1, denp, rsp, Pk, Wl, kc, lg);
    k_gemm2<<<dim3(32, 16), 256, 0, stream>>>(A, lg, P0);
    k_reduce<<<512, 256, 0, stream>>>(P0, out);
}

// Round 6
// 317.210 us; speedup vs baseline: 1.0982x; 1.0982x over previous
//
#include <hip/hip_runtime.h>
#include <math.h>

#define Nn 8192
#define Dd 256
#define Cc 16

// ---- workspace layout (floats) ----
// [0 .. 4M) : gemm1 bf16 partials (4 splits x Nn*Dd ushort = 16MB); later
//             gemm2 f32 partials (2M floats) reuse the front of it.
#define OFF_GT   4194304u    // bf16[256*8192] transposed G
#define OFF_LOG  5242880u    // logits f32 8192*16
#define OFF_G1B  5373952u    // bf16[8192] (gamma-1)
#define OFF_DEN  5378048u    // 4*8192 f32
#define OFF_RS   5410816u    // 4*8192 f32
#define OFF_KC   5443584u    // 64
#define WS_FLOATS 5443648u

typedef short vshort8 __attribute__((ext_vector_type(8)));
typedef float vfloat4 __attribute__((ext_vector_type(4)));

__device__ __forceinline__ float clip1(float x) {
    return fminf(fmaxf(x, -1.0f + 1e-7f), 1.0f - 1e-7f);
}

__device__ __forceinline__ unsigned short f2bf(float f) {
    unsigned int u = __float_as_uint(f);
    u += 0x7fff + ((u >> 16) & 1);          // round-to-nearest-even
    return (unsigned short)(u >> 16);
}

__device__ __forceinline__ float bf2f(unsigned short b) {
    return __uint_as_float(((unsigned int)b) << 16);
}

__device__ __forceinline__ float waveReduce(float v) {
    #pragma unroll
    for (int off = 32; off; off >>= 1) v += __shfl_down(v, off);
    return v;
}

__device__ __forceinline__ float blockReduceBcast(float v, float* red) {
    int t = threadIdx.x, w = t >> 6, l = t & 63;
    v = waveReduce(v);
    if (l == 0) red[w] = v;
    __syncthreads();
    if (t == 0) red[0] = red[0] + red[1] + red[2] + red[3];
    __syncthreads();
    float r = red[0];
    __syncthreads();
    return r;
}

// ---- K0: per-prototype constants ----
__global__ __launch_bounds__(256) void k_consts(const float* __restrict__ Wl,
                                                const float* __restrict__ Pk,
                                                float* __restrict__ kc) {
    __shared__ float red[8];
    int t = threadIdx.x, k = blockIdx.x;
    float pv = Pk[k * Dd + t];
    float wv = Wl[t * Cc + k];
    float p2 = blockReduceBcast(pv * pv, red);
    float pw = blockReduceBcast(pv * wv, red);
    float w2 = blockReduceBcast(wv * wv, red);
    if (t == 0) {
        float an  = fmaxf(sqrtf(w2), 1e-15f);
        float lam = 2.0f / fmaxf(1.0f - p2, 1e-10f);
        kc[k * 4 + 0] = p2; kc[k * 4 + 1] = pw;
        kc[k * 4 + 2] = an; kc[k * 4 + 3] = lam;
    }
}

// ---- K1: fused X@W^T (bf16 MFMA) + mobius rescale + gamma -> Gt, g1b ----
// One block per 32 rows; BN=256 (full width) so each block owns whole rows.
__global__ __launch_bounds__(256) void k_front(const float* __restrict__ X,
                                               const float* __restrict__ W,
                                               unsigned short* __restrict__ Gt,
                                               unsigned short* __restrict__ g1b) {
    __shared__ __align__(16) unsigned short Xs[32][256];  // swizzled bf16 X tile
    __shared__ __align__(16) unsigned short Gs[32][258];  // padded, for transpose
    __shared__ float xs2[32];
    __shared__ float scal[32];
    __shared__ float red4[32][4];

    const int t = threadIdx.x;
    const int l = t & 63, w = t >> 6;
    const int ll = l & 15, kh = l >> 4;
    const int m0 = blockIdx.x * 32;
    const int ar = t >> 3, aq = t & 7;
    const int c0 = w * 64;

    // ---- stage X (bf16, XOR swizzle) + per-thread |x|^2 partial ----
    float x2p = 0.f;
    #pragma unroll
    for (int tc = 0; tc < 4; ++tc) {
        const float* xp = &X[(size_t)(m0 + ar) * Dd + tc * 64 + aq * 8];
        vfloat4 v0 = *(const vfloat4*)xp;
        vfloat4 v1 = *(const vfloat4*)(xp + 4);
        vshort8 o;
        #pragma unroll
        for (int e = 0; e < 4; ++e) {
            x2p += v0[e] * v0[e] + v1[e] * v1[e];
            o[e] = (short)f2bf(v0[e]);
            o[e + 4] = (short)f2bf(v1[e]);
        }
        int byte = (tc * 64 + aq * 8) * 2;
        *(vshort8*)((char*)&Xs[ar][0] + (byte ^ ((ar & 7) << 4))) = o;
    }
    x2p += __shfl_xor(x2p, 1); x2p += __shfl_xor(x2p, 2); x2p += __shfl_xor(x2p, 4);
    if (aq == 0) xs2[ar] = x2p;
    __syncthreads();

    // ---- MFMA: mx = X @ W^T ; B frags straight from W rows ----
    vfloat4 acc[2][4];
    #pragma unroll
    for (int mi = 0; mi < 2; ++mi)
        #pragma unroll
        for (int ni = 0; ni < 4; ++ni)
            acc[mi][ni] = (vfloat4){0.f, 0.f, 0.f, 0.f};
    #pragma unroll
    for (int tc = 0; tc < 4; ++tc) {
        vshort8 bf[8];
        #pragma unroll
        for (int ni = 0; ni < 4; ++ni)
            #pragma unroll
            for (int kk = 0; kk < 2; ++kk) {
                const float* wp = &W[(size_t)(c0 + ni * 16 + ll) * Dd
                                     + tc * 64 + kh * 8 + kk * 32];
                vfloat4 b0 = *(const vfloat4*)wp;
                vfloat4 b1 = *(const vfloat4*)(wp + 4);
                vshort8 o;
                #pragma unroll
                for (int e = 0; e < 4; ++e) {
                    o[e] = (short)f2bf(b0[e]);
                    o[e + 4] = (short)f2bf(b1[e]);
                }
                bf[ni * 2 + kk] = o;
            }
        #pragma unroll
        for (int kk = 0; kk < 2; ++kk) {
            int byte = (tc * 64 + kh * 8 + kk * 32) * 2;
            vshort8 af[2];
            #pragma unroll
            for (int mi = 0; mi < 2; ++mi) {
                int row = mi * 16 + ll;
                af[mi] = *(const vshort8*)((const char*)&Xs[row][0]
                                           + (byte ^ ((row & 7) << 4)));
            }
            #pragma unroll
            for (int mi = 0; mi < 2; ++mi)
                #pragma unroll
                for (int ni = 0; ni < 4; ++ni)
                    acc[mi][ni] = __builtin_amdgcn_mfma_f32_16x16x32_bf16(
                        af[mi], bf[ni * 2 + kk], acc[mi][ni], 0, 0, 0);
        }
    }

    // ---- |mx|^2 per row: lane partial over its 4 cols, 16-lane shuffle, LDS ----
    #pragma unroll
    for (int mi = 0; mi < 2; ++mi)
        #pragma unroll
        for (int j = 0; j < 4; ++j) {
            float p = 0.f;
            #pragma unroll
            for (int ni = 0; ni < 4; ++ni)
                p += acc[mi][ni][j] * acc[mi][ni][j];
            p += __shfl_xor(p, 1); p += __shfl_xor(p, 2);
            p += __shfl_xor(p, 4); p += __shfl_xor(p, 8);
            if (ll == 0) red4[mi * 16 + kh * 4 + j][w] = p;
        }
    __syncthreads();

    // ---- per-row scalars: s, gamma ----
    if (t < 32) {
        float mx2 = red4[t][0] + red4[t][1] + red4[t][2] + red4[t][3];
        float xn = fmaxf(sqrtf(xs2[t]), 1e-15f);
        float mxn = fmaxf(sqrtf(mx2), 1e-15f);
        float s = tanhf(mxn / xn * atanhf(clip1(xn))) / mxn;
        float xw2 = s * s * mx2;                 // |xw|^2 = s^2 |mx|^2
        float gamma = 2.0f / fmaxf(1.0f - xw2, 1e-10f);
        scal[t] = gamma * s;
        g1b[m0 + t] = f2bf(gamma - 1.0f);
    }
    __syncthreads();

    // ---- G = scal[row] * mx -> Gs, then transposed write to Gt ----
    #pragma unroll
    for (int mi = 0; mi < 2; ++mi)
        #pragma unroll
        for (int ni = 0; ni < 4; ++ni) {
            int row = mi * 16 + kh * 4;
            int col = c0 + ni * 16 + ll;
            #pragma unroll
            for (int j = 0; j < 4; ++j)
                Gs[row + j][col] = f2bf(scal[row + j] * acc[mi][ni][j]);
        }
    __syncthreads();
    {
        int c = t;                               // one column per thread
        unsigned int pk[16];
        #pragma unroll
        for (int r2 = 0; r2 < 16; ++r2)
            pk[r2] = (unsigned int)Gs[2 * r2][c]
                   | ((unsigned int)Gs[2 * r2 + 1][c] << 16);
        uint4* dst = (uint4*)&Gt[(size_t)c * Nn + m0];
        #pragma unroll
        for (int q = 0; q < 4; ++q)
            dst[q] = make_uint4(pk[q * 4], pk[q * 4 + 1], pk[q * 4 + 2], pk[q * 4 + 3]);
    }
}

// ======== K2 helpers ========
__device__ __forceinline__ void load_bfrags(const unsigned short* const (&gtb)[4],
                                            int tc, vshort8 (&bf)[8]) {
    #pragma unroll
    for (int ni = 0; ni < 4; ++ni)
        #pragma unroll
        for (int kk = 0; kk < 2; ++kk)
            bf[ni * 2 + kk] = *(const vshort8*)(gtb[ni] + tc * 64 + kk * 32);
}

__device__ __forceinline__ void load_arow(const float* __restrict__ Abase,
                                          int tc, float (&a8)[8]) {
    const vfloat4* p = (const vfloat4*)(Abase + tc * 64);
    *(vfloat4*)&a8[0] = p[0];
    *(vfloat4*)&a8[4] = p[1];
}

__device__ __forceinline__ void cvt_fold(unsigned short (&Asb)[32][64],
        const unsigned short* g1s, const float (&ab)[8],
        int tile, int ar, int aq, float& dacc, float& racc) {
    vshort8 gv = *(const vshort8*)&g1s[tile * 64 + aq * 8];
    vshort8 o;
    #pragma unroll
    for (int e = 0; e < 8; ++e) {
        float av = ab[e];
        o[e] = (short)f2bf(av);
        dacc += av * bf2f((unsigned short)gv[e]);
        racc += av;
    }
    *(vshort8*)((char*)&Asb[ar][0] + ((aq * 16) ^ ((ar & 7) << 4))) = o;
}

__device__ __forceinline__ void phase_mfma(const unsigned short (&Asb)[32][64],
        const vshort8 (&bf)[8], int l, vfloat4 (&acc)[2][4]) {
    #pragma unroll
    for (int kk = 0; kk < 2; ++kk) {
        int ke2 = (kk * 32 + ((l >> 4) << 3)) * 2;
        vshort8 af[2];
        #pragma unroll
        for (int mi = 0; mi < 2; ++mi) {
            int row = mi * 16 + (l & 15);
            af[mi] = *(const vshort8*)((const char*)&Asb[row][0] + (ke2 ^ ((row & 7) << 4)));
        }
        #pragma unroll
        for (int mi = 0; mi < 2; ++mi)
            #pragma unroll
            for (int ni = 0; ni < 4; ++ni)
                acc[mi][ni] = __builtin_amdgcn_mfma_f32_16x16x32_bf16(
                    af[mi], bf[ni * 2 + kk], acc[mi][ni], 0, 0, 0);
    }
}

// ---- K2: bf16 partials[split] = A(k-slice) @ G ; den/rs folded in staging ----
// split-K=4 -> 1024 blocks -> 4 blocks/CU (16 waves/CU). B wave-private
// global->VGPR single-buffered; A via LDS dbuf; 1 barrier/phase, no vmcnt drain.
__global__ __launch_bounds__(256, 4) void k_gemm1_mfma(
        const float* __restrict__ A,
        const unsigned short* __restrict__ Gt,
        const unsigned short* __restrict__ g1b,
        unsigned short* __restrict__ Pp,
        float* __restrict__ denp,
        float* __restrict__ rsp) {
    __shared__ __align__(16) unsigned short As[2][32][64];   // 8 KB dbuf
    __shared__ __align__(16) unsigned short g1s[2048];       // 4 KB

    const int t = threadIdx.x;
    const int l = t & 63, w = t >> 6;
    const int id = blockIdx.x;
    const int splt = id & 3;                 // constant per XCD (id%8)
    const int m0 = (id >> 2) * 32;
    const int kb = splt * 2048;

    const int ar = t >> 3, aq = t & 7;
    const int c0 = w * 64;

    const unsigned short* gtb[4];
    #pragma unroll
    for (int ni = 0; ni < 4; ++ni)
        gtb[ni] = &Gt[(size_t)(c0 + ni * 16 + (l & 15)) * Nn + kb + ((l >> 4) << 3)];
    const float* Abase = &A[(size_t)(m0 + ar) * Nn + kb + aq * 8];

    vfloat4 acc[2][4];
    #pragma unroll
    for (int mi = 0; mi < 2; ++mi)
        #pragma unroll
        for (int ni = 0; ni < 4; ++ni)
            acc[mi][ni] = (vfloat4){0.f, 0.f, 0.f, 0.f};
    float dacc = 0.f, racc = 0.f;
    float a0[8], a1[8], a2[8], a3[8];        // raw A 4-ring, distance-3 issue

    // ---- prologue ----
    *(uint4*)&g1s[t * 8] = *(const uint4*)&g1b[kb + t * 8];
    load_arow(Abase, 0, a0);
    load_arow(Abase, 1, a1);
    load_arow(Abase, 2, a2);
    asm volatile("s_waitcnt lgkmcnt(0)" ::: "memory");
    __builtin_amdgcn_s_barrier();            // g1s visible
    cvt_fold(As[0], g1s, a0, 0, ar, aq, dacc, racc);
    asm volatile("s_waitcnt lgkmcnt(0)" ::: "memory");
    __builtin_amdgcn_s_barrier();            // As[0] visible

    // ---- 32 phases, unrolled x4 so all ring indices are literals ----
    for (int u = 0; u < 8; ++u) {
        #pragma unroll
        for (int pp = 0; pp < 4; ++pp) {
            const int p = u * 4 + pp;
            vshort8 bf[8];
            load_bfrags(gtb, p, bf);         // B for THIS tile (issued first)
            if (p < 29) {                    // A prefetch distance 3
                float (&adst)[8] = (pp == 0) ? a3 : (pp == 1) ? a0
                                 : (pp == 2) ? a1 : a2;
                load_arow(Abase, p + 3, adst);
            }
            if (p < 31) {                    // stage A tile p+1 (fills B latency)
                float (&asrc)[8] = (pp == 0) ? a1 : (pp == 1) ? a2
                                 : (pp == 2) ? a3 : a0;
                if (pp & 1) cvt_fold(As[0], g1s, asrc, p + 1, ar, aq, dacc, racc);
                else        cvt_fold(As[1], g1s, asrc, p + 1, ar, aq, dacc, racc);
            }
            if (pp & 1) phase_mfma(As[1], bf, l, acc);
            else        phase_mfma(As[0], bf, l, acc);
            asm volatile("s_waitcnt lgkmcnt(0)" ::: "memory");
            __builtin_amdgcn_s_barrier();
        }
    }

    // ---- den/rs ----
    dacc += __shfl_xor(dacc, 1); dacc += __shfl_xor(dacc, 2); dacc += __shfl_xor(dacc, 4);
    racc += __shfl_xor(racc, 1); racc += __shfl_xor(racc, 2); racc += __shfl_xor(racc, 4);
    if (aq == 0) {
        denp[splt * Nn + m0 + ar] = dacc;
        rsp[splt * Nn + m0 + ar] = racc;
    }

    // ---- store bf16 partial ----
    unsigned short* P = Pp + (size_t)splt * ((size_t)Nn * Dd);
    #pragma unroll
    for (int mi = 0; mi < 2; ++mi)
        #pragma unroll
        for (int ni = 0; ni < 4; ++ni) {
            int row = m0 + mi * 16 + ((l >> 4) << 2);
            int col = c0 + ni * 16 + (l & 15);
            #pragma unroll
            for (int j = 0; j < 4; ++j)
                P[(size_t)(row + j) * Dd + col] = f2bf(acc[mi][ni][j]);
        }
}

// ---- K3: per-row gyromidpoint chain + H1 + hyperbolic logits ----
__global__ __launch_bounds__(256) void k_rowfix(const unsigned short* __restrict__ Pp,
                                                const float* __restrict__ denp,
                                                const float* __restrict__ rsp,
                                                const float* __restrict__ Pk,
                                                const float* __restrict__ Wl,
                                                const float* __restrict__ kc,
                                                float* __restrict__ logits) {
    __shared__ float red[8];
    __shared__ float hs[256];
    __shared__ float PQ[16][2];
    int i = blockIdx.x, t = threadIdx.x;
    float nom = 0.f;
    #pragma unroll
    for (int s = 0; s < 4; ++s)
        nom += bf2f(Pp[(size_t)s * Nn * Dd + (size_t)i * Dd + t]);
    float dv = denp[i] + denp[Nn + i] + denp[2 * Nn + i] + denp[3 * Nn + i];
    dv = (fabsf(dv) < 1e-10f) ? 1e-10f : dv;
    float tm = nom / dv;
    float r2 = blockReduceBcast(tm * tm, red);
    float r = fmaxf(sqrtf(r2), 1e-15f);
    float mmul = tanhf(0.5f * atanhf(clip1(r))) / r;
    float mj = mmul * tm;
    float mn2 = blockReduceBcast(mj * mj, red);
    float mn = fmaxf(sqrtf(mn2), 1e-15f);
    float sA = rsp[i] + rsp[Nn + i] + rsp[2 * Nn + i] + rsp[3 * Nn + i];
    float axmul = tanhf(sA * atanhf(clip1(mn))) / mn;
    float axw = axmul * mj;
    float yn2 = blockReduceBcast(axw * axw, red);
    float yn = fmaxf(sqrtf(yn2), 1e-15f);
    float v = atanhf(clip1(yn)) / yn * axw;
    float u = fmaxf(v, 0.0f);
    float un2 = blockReduceBcast(u * u, red);
    float un = fmaxf(sqrtf(un2), 1e-15f);
    float h = tanhf(un) / un * u;
    float h2 = blockReduceBcast(h * h, red);
    hs[t] = h;
    __syncthreads();
    int w = t >> 6, l = t & 63;
    #pragma unroll
    for (int kk = 0; kk < 4; ++kk) {
        int k = w * 4 + kk;
        float pp = 0.f, qq = 0.f;
        #pragma unroll
        for (int m = 0; m < 4; ++m) {
            float hv = hs[l + 64 * m];
            pp += hv * Pk[k * Dd + l + 64 * m];
            qq += hv * Wl[(l + 64 * m) * Cc + k];
        }
        pp = waveReduce(pp);
        qq = waveReduce(qq);
        if (l == 0) { PQ[k][0] = pp; PQ[k][1] = qq; }
    }
    __syncthreads();
    if (t < 16) {
        int k = t;
        float p2 = kc[k * 4 + 0], pw = kc[k * 4 + 1];
        float an = kc[k * 4 + 2], lam = kc[k * 4 + 3];
        float P = PQ[k][0], Q = PQ[k][1];
        float alpha = 1.0f - 2.0f * P + h2;
        float beta  = 1.0f - p2;
        float Dm = fmaxf(1.0f - 2.0f * P + p2 * h2, 1e-15f);
        float za  = (-alpha * pw + beta * Q) / Dm;
        float zn2 = (alpha * alpha * p2 - 2.0f * alpha * beta * P + beta * beta * h2)
                    / (Dm * Dm);
        float dd = fmaxf(1.0f - zn2, 1e-10f) * an;
        float dist = asinhf(2.0f * za / dd);
        logits[(size_t)i * Cc + k] = lam * an * dist;
    }
}

// ---- K4: partials of out = A @ logits (j-split x16) ----
__global__ __launch_bounds__(256) void k_gemm2(const float* __restrict__ A,
                                               const float* __restrict__ L,
                                               float* __restrict__ part) {
    __shared__ __align__(16) float Ls[64 * 20];
    __shared__ float Pacc[256 * 16];
    int t = threadIdx.x;
    int r0 = blockIdx.x * 256;
    int jbase = blockIdx.y * 512;
    int q = t & 3, g = t >> 2;
    float acc[4][16] = {};
    for (int jc = 0; jc < 512; jc += 64) {
        {
            int jrow = t >> 2, kq = t & 3;
            *(float4*)&Ls[jrow * 20 + kq * 4] =
                *(const float4*)&L[(size_t)(jbase + jc + jrow) * Cc + kq * 4];
        }
        __syncthreads();
        #pragma unroll
        for (int m = 0; m < 4; ++m) {
            int jl = m * 16 + q * 4;
            float av[4][4];
            #pragma unroll
            for (int rr = 0; rr < 4; ++rr) {
                float4 tmp = *(const float4*)&A[(size_t)(r0 + g * 4 + rr) * Nn
                                                + jbase + jc + jl];
                av[rr][0] = tmp.x; av[rr][1] = tmp.y;
                av[rr][2] = tmp.z; av[rr][3] = tmp.w;
            }
            #pragma unroll
            for (int jj = 0; jj < 4; ++jj) {
                const float* lr = &Ls[(jl + jj) * 20];
                float lv[16];
                #pragma unroll
                for (int k2 = 0; k2 < 16; k2 += 4) {
                    float4 lt = *(const float4*)&lr[k2];
                    lv[k2] = lt.x; lv[k2 + 1] = lt.y;
                    lv[k2 + 2] = lt.z; lv[k2 + 3] = lt.w;
                }
                #pragma unroll
                for (int rr = 0; rr < 4; ++rr)
                    #pragma unroll
                    for (int k2 = 0; k2 < 16; ++k2)
                        acc[rr][k2] += av[rr][jj] * lv[k2];
            }
        }
        __syncthreads();
    }
    for (int ii = t; ii < 4096; ii += 256) Pacc[ii] = 0.f;
    __syncthreads();
    for (int qq = 0; qq < 4; ++qq) {
        if (q == qq) {
            #pragma unroll
            for (int rr = 0; rr < 4; ++rr)
                #pragma unroll
                for (int k2 = 0; k2 < 16; ++k2)
                    Pacc[(g * 4 + rr) * 16 + k2] += acc[rr][k2];
        }
        __syncthreads();
    }
    float* dst = &part[(size_t)blockIdx.y * (Nn * Cc) + (size_t)r0 * Cc];
    for (int ii = t * 4; ii < 4096; ii += 1024)
        *(float4*)&dst[ii] = *(const float4*)&Pacc[ii];
}

// ---- K5: reduce j-split partials ----
__global__ __launch_bounds__(256) void k_reduce(const float* __restrict__ part,
                                                float* __restrict__ out) {
    int i = blockIdx.x * 256 + threadIdx.x;
    float s = 0.f;
    #pragma unroll
    for (int j = 0; j < 16; ++j) s += part[(size_t)j * (Nn * Cc) + i];
    out[i] = s;
}

extern "C" void kernel_launch(void* const* d_in, const int* in_sizes, int n_in,
                              void* d_out, int out_size, void* d_ws, size_t ws_size,
                              hipStream_t stream) {
    const float* X  = (const float*)d_in[0];
    const float* A  = (const float*)d_in[1];
    const float* W  = (const float*)d_in[2];
    const float* Wl = (const float*)d_in[3];
    const float* Pk = (const float*)d_in[4];
    float* out = (float*)d_out;
    float* ws = (float*)d_ws;
    if (ws_size < (size_t)WS_FLOATS * sizeof(float)) return;

    unsigned short* Pp  = (unsigned short*)ws;      // 4 bf16 partials (16MB)
    float* part = ws;                               // gemm2 f32 partials (8MB, later)
    unsigned short* Gt  = (unsigned short*)(ws + OFF_GT);
    float* lg   = ws + OFF_LOG;
    unsigned short* g1b = (unsigned short*)(ws + OFF_G1B);
    float* denp = ws + OFF_DEN;
    float* rsp  = ws + OFF_RS;
    float* kc   = ws + OFF_KC;

    k_consts<<<16, 256, 0, stream>>>(Wl, Pk, kc);
    k_front<<<256, 256, 0, stream>>>(X, W, Gt, g1b);
    k_gemm1_mfma<<<1024, 256, 0, stream>>>(A, Gt, g1b, Pp, denp, rsp);
    k_rowfix<<<Nn, 256, 0, stream>>>(Pp, denp, rsp, Pk, Wl, kc, lg);
    k_gemm2<<<dim3(32, 16), 256, 0, stream>>>(A, lg, part);
    k_reduce<<<512, 256, 0, stream>>>(part, out);
}

// Round 7
// 228.633 us; speedup vs baseline: 1.5237x; 1.3874x over previous
//
#include <hip/hip_runtime.h>
#include <math.h>

#define Nn 8192
#define Dd 256
#define Cc 16

// ---- workspace layout (floats) ----
// [0 .. 4M) : gemm1 bf16 partials (4 splits x Nn*Dd ushort = 16MB); later
//             gemm2 f32 partials (2M floats) reuse the front of it.
#define OFF_BP   4194304u    // bf16 packed B fragments (4 MB)
#define OFF_LOG  5242880u    // logits f32 8192*16
#define OFF_G1B  5373952u    // bf16[8192] (gamma-1)
#define OFF_DEN  5378048u    // 4*8192 f32
#define OFF_RS   5410816u    // 4*8192 f32
#define OFF_KC   5443584u    // 64
#define WS_FLOATS 5443648u

typedef short vshort8 __attribute__((ext_vector_type(8)));
typedef float vfloat4 __attribute__((ext_vector_type(4)));

#define AS1 __attribute__((address_space(1)))
#define AS3 __attribute__((address_space(3)))

__device__ __forceinline__ float clip1(float x) {
    return fminf(fmaxf(x, -1.0f + 1e-7f), 1.0f - 1e-7f);
}

__device__ __forceinline__ unsigned short f2bf(float f) {
    unsigned int u = __float_as_uint(f);
    u += 0x7fff + ((u >> 16) & 1);          // round-to-nearest-even
    return (unsigned short)(u >> 16);
}

__device__ __forceinline__ float bf2f(unsigned short b) {
    return __uint_as_float(((unsigned int)b) << 16);
}

__device__ __forceinline__ float waveReduce(float v) {
    #pragma unroll
    for (int off = 32; off; off >>= 1) v += __shfl_down(v, off);
    return v;
}

__device__ __forceinline__ float blockReduceBcast(float v, float* red) {
    int t = threadIdx.x, w = t >> 6, l = t & 63;
    v = waveReduce(v);
    if (l == 0) red[w] = v;
    __syncthreads();
    if (t == 0) red[0] = red[0] + red[1] + red[2] + red[3];
    __syncthreads();
    float r = red[0];
    __syncthreads();
    return r;
}

// ---- K0: per-prototype constants ----
__global__ __launch_bounds__(256) void k_consts(const float* __restrict__ Wl,
                                                const float* __restrict__ Pk,
                                                float* __restrict__ kc) {
    __shared__ float red[8];
    int t = threadIdx.x, k = blockIdx.x;
    float pv = Pk[k * Dd + t];
    float wv = Wl[t * Cc + k];
    float p2 = blockReduceBcast(pv * pv, red);
    float pw = blockReduceBcast(pv * wv, red);
    float w2 = blockReduceBcast(wv * wv, red);
    if (t == 0) {
        float an  = fmaxf(sqrtf(w2), 1e-15f);
        float lam = 2.0f / fmaxf(1.0f - p2, 1e-10f);
        kc[k * 4 + 0] = p2; kc[k * 4 + 1] = pw;
        kc[k * 4 + 2] = an; kc[k * 4 + 3] = lam;
    }
}

// ---- K1: fused X@W^T (bf16 MFMA) + mobius rescale + gamma -> packed B ----
// Block handles rows m0..m0+31 of G == k-slab s = blockIdx.x of gemm1's B.
// Output layout: Bp chunk ((s*16 + g*4 + ni)*64 + lane) holds the vshort8
// fragment data for (col = g*64+ni*16+(lane&15), k = s*32+(lane>>4)*8+e).
__global__ __launch_bounds__(256) void k_front(const float* __restrict__ X,
                                               const float* __restrict__ W,
                                               unsigned short* __restrict__ Bp,
                                               unsigned short* __restrict__ g1b) {
    __shared__ __align__(16) unsigned short Xs[32][256];  // swizzled bf16 X tile
    __shared__ __align__(16) unsigned short Gs[32][258];  // padded [k-local][col]
    __shared__ float xs2[32];
    __shared__ float scal[32];
    __shared__ float red4[32][4];

    const int t = threadIdx.x;
    const int l = t & 63, w = t >> 6;
    const int ll = l & 15, kh = l >> 4;
    const int m0 = blockIdx.x * 32;
    const int ar = t >> 3, aq = t & 7;
    const int c0 = w * 64;

    // ---- stage X (bf16, XOR swizzle) + per-thread |x|^2 partial ----
    float x2p = 0.f;
    #pragma unroll
    for (int tc = 0; tc < 4; ++tc) {
        const float* xp = &X[(size_t)(m0 + ar) * Dd + tc * 64 + aq * 8];
        vfloat4 v0 = *(const vfloat4*)xp;
        vfloat4 v1 = *(const vfloat4*)(xp + 4);
        vshort8 o;
        #pragma unroll
        for (int e = 0; e < 4; ++e) {
            x2p += v0[e] * v0[e] + v1[e] * v1[e];
            o[e] = (short)f2bf(v0[e]);
            o[e + 4] = (short)f2bf(v1[e]);
        }
        int byte = (tc * 64 + aq * 8) * 2;
        *(vshort8*)((char*)&Xs[ar][0] + (byte ^ ((ar & 7) << 4))) = o;
    }
    x2p += __shfl_xor(x2p, 1); x2p += __shfl_xor(x2p, 2); x2p += __shfl_xor(x2p, 4);
    if (aq == 0) xs2[ar] = x2p;
    __syncthreads();

    // ---- MFMA: mx = X @ W^T ; B frags straight from W rows ----
    vfloat4 acc[2][4];
    #pragma unroll
    for (int mi = 0; mi < 2; ++mi)
        #pragma unroll
        for (int ni = 0; ni < 4; ++ni)
            acc[mi][ni] = (vfloat4){0.f, 0.f, 0.f, 0.f};
    #pragma unroll
    for (int tc = 0; tc < 4; ++tc) {
        vshort8 bf[8];
        #pragma unroll
        for (int ni = 0; ni < 4; ++ni)
            #pragma unroll
            for (int kk = 0; kk < 2; ++kk) {
                const float* wp = &W[(size_t)(c0 + ni * 16 + ll) * Dd
                                     + tc * 64 + kh * 8 + kk * 32];
                vfloat4 b0 = *(const vfloat4*)wp;
                vfloat4 b1 = *(const vfloat4*)(wp + 4);
                vshort8 o;
                #pragma unroll
                for (int e = 0; e < 4; ++e) {
                    o[e] = (short)f2bf(b0[e]);
                    o[e + 4] = (short)f2bf(b1[e]);
                }
                bf[ni * 2 + kk] = o;
            }
        #pragma unroll
        for (int kk = 0; kk < 2; ++kk) {
            int byte = (tc * 64 + kh * 8 + kk * 32) * 2;
            vshort8 af[2];
            #pragma unroll
            for (int mi = 0; mi < 2; ++mi) {
                int row = mi * 16 + ll;
                af[mi] = *(const vshort8*)((const char*)&Xs[row][0]
                                           + (byte ^ ((row & 7) << 4)));
            }
            #pragma unroll
            for (int mi = 0; mi < 2; ++mi)
                #pragma unroll
                for (int ni = 0; ni < 4; ++ni)
                    acc[mi][ni] = __builtin_amdgcn_mfma_f32_16x16x32_bf16(
                        af[mi], bf[ni * 2 + kk], acc[mi][ni], 0, 0, 0);
        }
    }

    // ---- |mx|^2 per row ----
    #pragma unroll
    for (int mi = 0; mi < 2; ++mi)
        #pragma unroll
        for (int j = 0; j < 4; ++j) {
            float p = 0.f;
            #pragma unroll
            for (int ni = 0; ni < 4; ++ni)
                p += acc[mi][ni][j] * acc[mi][ni][j];
            p += __shfl_xor(p, 1); p += __shfl_xor(p, 2);
            p += __shfl_xor(p, 4); p += __shfl_xor(p, 8);
            if (ll == 0) red4[mi * 16 + kh * 4 + j][w] = p;
        }
    __syncthreads();

    // ---- per-row scalars: s, gamma ----
    if (t < 32) {
        float mx2 = red4[t][0] + red4[t][1] + red4[t][2] + red4[t][3];
        float xn = fmaxf(sqrtf(xs2[t]), 1e-15f);
        float mxn = fmaxf(sqrtf(mx2), 1e-15f);
        float s = tanhf(mxn / xn * atanhf(clip1(xn))) / mxn;
        float xw2 = s * s * mx2;                 // |xw|^2 = s^2 |mx|^2
        float gamma = 2.0f / fmaxf(1.0f - xw2, 1e-10f);
        scal[t] = gamma * s;
        g1b[m0 + t] = f2bf(gamma - 1.0f);
    }
    __syncthreads();

    // ---- G = scal[row] * mx -> Gs [k-local][col] ----
    #pragma unroll
    for (int mi = 0; mi < 2; ++mi)
        #pragma unroll
        for (int ni = 0; ni < 4; ++ni) {
            int row = mi * 16 + kh * 4;
            int col = c0 + ni * 16 + ll;
            #pragma unroll
            for (int j = 0; j < 4; ++j)
                Gs[row + j][col] = f2bf(scal[row + j] * acc[mi][ni][j]);
        }
    __syncthreads();

    // ---- pack into fragment-major Bp (coalesced 16B per thread) ----
    const int s = blockIdx.x;
    #pragma unroll
    for (int pass = 0; pass < 4; ++pass) {
        int c = pass * 256 + t;
        int gni = c >> 6, lc = c & 63;
        int col = (gni >> 2) * 64 + (gni & 3) * 16 + (lc & 15);
        int kh8 = (lc >> 4) * 8;
        vshort8 o;
        #pragma unroll
        for (int e = 0; e < 8; ++e) o[e] = (short)Gs[kh8 + e][col];
        *(vshort8*)&Bp[((size_t)(s * 16 + gni) * 64 + lc) * 8] = o;
    }
}

// ---- K2: bf16 partials[split] = A(k-slice) @ G ----
// BM=32, BN=256, BK=128, split-K=4 -> 1024 blocks, 4 blocks/CU.
// A: global_load_lds fp32 (source pre-XOR-swizzled), dbuf 2x16KB.
// B: packed fragment loads, fully coalesced, regs (2 batches of 8).
// den/rs folded by wave 0 from the fp32 frag reads.
__global__ __launch_bounds__(256, 4) void k_gemm1_mfma(
        const float* __restrict__ A,
        const unsigned short* __restrict__ Bp,
        const unsigned short* __restrict__ g1b,
        unsigned short* __restrict__ Pp,
        float* __restrict__ denp,
        float* __restrict__ rsp) {
    __shared__ __align__(16) float As[2][32 * 128];      // 32 KB dbuf
    __shared__ __align__(16) unsigned short g1s[2048];   // 4 KB

    const int t = threadIdx.x, l = t & 63, w = t >> 6;
    const int id = blockIdx.x;
    const int splt = id & 3;                 // constant per XCD (id%8)
    const int m0 = (id >> 2) * 32;
    const int kb = splt * 2048;
    const int kh = l >> 4, ll15 = l & 15;

    // A gload source pointers (4 instrs/wave; chunk q = w*256+i*64+l)
    const float* asrc[4];
    #pragma unroll
    for (int i = 0; i < 4; ++i) {
        int q = w * 256 + i * 64 + l;
        int row = q >> 5, c = q & 31;
        asrc[i] = &A[(size_t)(m0 + row) * Nn + kb + ((c ^ (row & 7)) << 2)];
    }
    // B packed base: elem = (splt*1024 + p*64 + ss*16 + w*4 + ni)*512 + l*8
    const unsigned short* bB = Bp + (size_t)(splt * 1024 + w * 4) * 512 + l * 8;

    vfloat4 acc[2][4];
    #pragma unroll
    for (int mi = 0; mi < 2; ++mi)
        #pragma unroll
        for (int ni = 0; ni < 4; ++ni)
            acc[mi][ni] = (vfloat4){0.f, 0.f, 0.f, 0.f};
    float dacc[2] = {0.f, 0.f}, racc[2] = {0.f, 0.f};

    // ---- prologue: g1 slice + A tile 0 ----
    *(uint4*)&g1s[t * 8] = *(const uint4*)&g1b[kb + t * 8];
    #pragma unroll
    for (int i = 0; i < 4; ++i)
        __builtin_amdgcn_global_load_lds((const AS1 unsigned int*)asrc[i],
            (AS3 unsigned int*)&As[0][w * 1024 + i * 256], 16, 0, 0);
    __syncthreads();

    for (int p = 0; p < 16; ++p) {
        const int cur = p & 1;
        const unsigned short* bp = bB + p * 32768;
        vshort8 bf[8];
        #pragma unroll
        for (int h = 0; h < 2; ++h) {
            // load B batch h (slabs 2h, 2h+1) -- coalesced 1KB/instr
            #pragma unroll
            for (int s2 = 0; s2 < 2; ++s2)
                #pragma unroll
                for (int ni = 0; ni < 4; ++ni)
                    bf[s2 * 4 + ni] = *(const vshort8*)
                        (bp + ((h * 2 + s2) * 16 + ni) * 512);
            if (h == 0 && p < 15) {          // A gload for p+1 under batch-0
                #pragma unroll
                for (int i = 0; i < 4; ++i)
                    __builtin_amdgcn_global_load_lds(
                        (const AS1 unsigned int*)(asrc[i] + (p + 1) * 128),
                        (AS3 unsigned int*)&As[cur ^ 1][w * 1024 + i * 256],
                        16, 0, 0);
            }
            #pragma unroll
            for (int s2 = 0; s2 < 2; ++s2) {
                const int ss = h * 2 + s2;
                vshort8 gv;
                if (w == 0)
                    gv = *(const vshort8*)&g1s[p * 128 + ss * 32 + kh * 8];
                vshort8 af[2];
                #pragma unroll
                for (int mi = 0; mi < 2; ++mi) {
                    int row = mi * 16 + ll15;
                    int ba = row * 512 + (((ss * 8 + kh * 2) ^ (row & 7)) << 4);
                    vfloat4 v0 = *(const vfloat4*)((const char*)&As[cur][0] + ba);
                    vfloat4 v1 = *(const vfloat4*)((const char*)&As[cur][0] + (ba ^ 16));
                    vshort8 o;
                    #pragma unroll
                    for (int e = 0; e < 4; ++e) {
                        o[e] = (short)f2bf(v0[e]);
                        o[e + 4] = (short)f2bf(v1[e]);
                    }
                    af[mi] = o;
                    if (w == 0) {
                        #pragma unroll
                        for (int e = 0; e < 4; ++e) {
                            dacc[mi] += v0[e] * bf2f((unsigned short)gv[e])
                                      + v1[e] * bf2f((unsigned short)gv[e + 4]);
                            racc[mi] += v0[e] + v1[e];
                        }
                    }
                }
                #pragma unroll
                for (int mi = 0; mi < 2; ++mi)
                    #pragma unroll
                    for (int ni = 0; ni < 4; ++ni)
                        acc[mi][ni] = __builtin_amdgcn_mfma_f32_16x16x32_bf16(
                            af[mi], bf[s2 * 4 + ni], acc[mi][ni], 0, 0, 0);
            }
        }
        __syncthreads();
    }

    // ---- den/rs (wave 0 saw every A element exactly once) ----
    if (w == 0) {
        #pragma unroll
        for (int mi = 0; mi < 2; ++mi) {
            dacc[mi] += __shfl_xor(dacc[mi], 16);
            dacc[mi] += __shfl_xor(dacc[mi], 32);
            racc[mi] += __shfl_xor(racc[mi], 16);
            racc[mi] += __shfl_xor(racc[mi], 32);
        }
        if (l < 16) {
            #pragma unroll
            for (int mi = 0; mi < 2; ++mi) {
                denp[splt * Nn + m0 + mi * 16 + l] = dacc[mi];
                rsp [splt * Nn + m0 + mi * 16 + l] = racc[mi];
            }
        }
    }

    // ---- store bf16 partial ----
    unsigned short* P = Pp + (size_t)splt * ((size_t)Nn * Dd);
    #pragma unroll
    for (int mi = 0; mi < 2; ++mi)
        #pragma unroll
        for (int ni = 0; ni < 4; ++ni) {
            int row = m0 + mi * 16 + (kh << 2);
            int col = w * 64 + ni * 16 + ll15;
            #pragma unroll
            for (int j = 0; j < 4; ++j)
                P[(size_t)(row + j) * Dd + col] = f2bf(acc[mi][ni][j]);
        }
}

// ---- K3: per-row gyromidpoint chain + H1 + hyperbolic logits ----
__global__ __launch_bounds__(256) void k_rowfix(const unsigned short* __restrict__ Pp,
                                                const float* __restrict__ denp,
                                                const float* __restrict__ rsp,
                                                const float* __restrict__ Pk,
                                                const float* __restrict__ Wl,
                                                const float* __restrict__ kc,
                                                float* __restrict__ logits) {
    __shared__ float red[8];
    __shared__ float hs[256];
    __shared__ float PQ[16][2];
    int i = blockIdx.x, t = threadIdx.x;
    float nom = 0.f;
    #pragma unroll
    for (int s = 0; s < 4; ++s)
        nom += bf2f(Pp[(size_t)s * Nn * Dd + (size_t)i * Dd + t]);
    float dv = denp[i] + denp[Nn + i] + denp[2 * Nn + i] + denp[3 * Nn + i];
    dv = (fabsf(dv) < 1e-10f) ? 1e-10f : dv;
    float tm = nom / dv;
    float r2 = blockReduceBcast(tm * tm, red);
    float r = fmaxf(sqrtf(r2), 1e-15f);
    float mmul = tanhf(0.5f * atanhf(clip1(r))) / r;
    float mj = mmul * tm;
    float mn2 = blockReduceBcast(mj * mj, red);
    float mn = fmaxf(sqrtf(mn2), 1e-15f);
    float sA = rsp[i] + rsp[Nn + i] + rsp[2 * Nn + i] + rsp[3 * Nn + i];
    float axmul = tanhf(sA * atanhf(clip1(mn))) / mn;
    float axw = axmul * mj;
    float yn2 = blockReduceBcast(axw * axw, red);
    float yn = fmaxf(sqrtf(yn2), 1e-15f);
    float v = atanhf(clip1(yn)) / yn * axw;
    float u = fmaxf(v, 0.0f);
    float un2 = blockReduceBcast(u * u, red);
    float un = fmaxf(sqrtf(un2), 1e-15f);
    float h = tanhf(un) / un * u;
    float h2 = blockReduceBcast(h * h, red);
    hs[t] = h;
    __syncthreads();
    int w = t >> 6, l = t & 63;
    #pragma unroll
    for (int kk = 0; kk < 4; ++kk) {
        int k = w * 4 + kk;
        float pp = 0.f, qq = 0.f;
        #pragma unroll
        for (int m = 0; m < 4; ++m) {
            float hv = hs[l + 64 * m];
            pp += hv * Pk[k * Dd + l + 64 * m];
            qq += hv * Wl[(l + 64 * m) * Cc + k];
        }
        pp = waveReduce(pp);
        qq = waveReduce(qq);
        if (l == 0) { PQ[k][0] = pp; PQ[k][1] = qq; }
    }
    __syncthreads();
    if (t < 16) {
        int k = t;
        float p2 = kc[k * 4 + 0], pw = kc[k * 4 + 1];
        float an = kc[k * 4 + 2], lam = kc[k * 4 + 3];
        float P = PQ[k][0], Q = PQ[k][1];
        float alpha = 1.0f - 2.0f * P + h2;
        float beta  = 1.0f - p2;
        float Dm = fmaxf(1.0f - 2.0f * P + p2 * h2, 1e-15f);
        float za  = (-alpha * pw + beta * Q) / Dm;
        float zn2 = (alpha * alpha * p2 - 2.0f * alpha * beta * P + beta * beta * h2)
                    / (Dm * Dm);
        float dd = fmaxf(1.0f - zn2, 1e-10f) * an;
        float dist = asinhf(2.0f * za / dd);
        logits[(size_t)i * Cc + k] = lam * an * dist;
    }
}

// ---- K4: partials of out = A @ logits (j-split x16) ----
__global__ __launch_bounds__(256) void k_gemm2(const float* __restrict__ A,
                                               const float* __restrict__ L,
                                               float* __restrict__ part) {
    __shared__ __align__(16) float Ls[64 * 20];
    __shared__ float Pacc[256 * 16];
    int t = threadIdx.x;
    int r0 = blockIdx.x * 256;
    int jbase = blockIdx.y * 512;
    int q = t & 3, g = t >> 2;
    float acc[4][16] = {};
    for (int jc = 0; jc < 512; jc += 64) {
        {
            int jrow = t >> 2, kq = t & 3;
            *(float4*)&Ls[jrow * 20 + kq * 4] =
                *(const float4*)&L[(size_t)(jbase + jc + jrow) * Cc + kq * 4];
        }
        __syncthreads();
        #pragma unroll
        for (int m = 0; m < 4; ++m) {
            int jl = m * 16 + q * 4;
            float av[4][4];
            #pragma unroll
            for (int rr = 0; rr < 4; ++rr) {
                float4 tmp = *(const float4*)&A[(size_t)(r0 + g * 4 + rr) * Nn
                                                + jbase + jc + jl];
                av[rr][0] = tmp.x; av[rr][1] = tmp.y;
                av[rr][2] = tmp.z; av[rr][3] = tmp.w;
            }
            #pragma unroll
            for (int jj = 0; jj < 4; ++jj) {
                const float* lr = &Ls[(jl + jj) * 20];
                float lv[16];
                #pragma unroll
                for (int k2 = 0; k2 < 16; k2 += 4) {
                    float4 lt = *(const float4*)&lr[k2];
                    lv[k2] = lt.x; lv[k2 + 1] = lt.y;
                    lv[k2 + 2] = lt.z; lv[k2 + 3] = lt.w;
                }
                #pragma unroll
                for (int rr = 0; rr < 4; ++rr)
                    #pragma unroll
                    for (int k2 = 0; k2 < 16; ++k2)
                        acc[rr][k2] += av[rr][jj] * lv[k2];
            }
        }
        __syncthreads();
    }
    for (int ii = t; ii < 4096; ii += 256) Pacc[ii] = 0.f;
    __syncthreads();
    for (int qq = 0; qq < 4; ++qq) {
        if (q == qq) {
            #pragma unroll
            for (int rr = 0; rr < 4; ++rr)
                #pragma unroll
                for (int k2 = 0; k2 < 16; ++k2)
                    Pacc[(g * 4 + rr) * 16 + k2] += acc[rr][k2];
        }
        __syncthreads();
    }
    float* dst = &part[(size_t)blockIdx.y * (Nn * Cc) + (size_t)r0 * Cc];
    for (int ii = t * 4; ii < 4096; ii += 1024)
        *(float4*)&dst[ii] = *(const float4*)&Pacc[ii];
}

// ---- K5: reduce j-split partials ----
__global__ __launch_bounds__(256) void k_reduce(const float* __restrict__ part,
                                                float* __restrict__ out) {
    int i = blockIdx.x * 256 + threadIdx.x;
    float s = 0.f;
    #pragma unroll
    for (int j = 0; j < 16; ++j) s += part[(size_t)j * (Nn * Cc) + i];
    out[i] = s;
}

extern "C" void kernel_launch(void* const* d_in, const int* in_sizes, int n_in,
                              void* d_out, int out_size, void* d_ws, size_t ws_size,
                              hipStream_t stream) {
    const float* X  = (const float*)d_in[0];
    const float* A  = (const float*)d_in[1];
    const float* W  = (const float*)d_in[2];
    const float* Wl = (const float*)d_in[3];
    const float* Pk = (const float*)d_in[4];
    float* out = (float*)d_out;
    float* ws = (float*)d_ws;
    if (ws_size < (size_t)WS_FLOATS * sizeof(float)) return;

    unsigned short* Pp  = (unsigned short*)ws;      // 4 bf16 partials (16MB)
    float* part = ws;                               // gemm2 f32 partials (8MB, later)
    unsigned short* Bp  = (unsigned short*)(ws + OFF_BP);
    float* lg   = ws + OFF_LOG;
    unsigned short* g1b = (unsigned short*)(ws + OFF_G1B);
    float* denp = ws + OFF_DEN;
    float* rsp  = ws + OFF_RS;
    float* kc   = ws + OFF_KC;

    k_consts<<<16, 256, 0, stream>>>(Wl, Pk, kc);
    k_front<<<256, 256, 0, stream>>>(X, W, Bp, g1b);
    k_gemm1_mfma<<<1024, 256, 0, stream>>>(A, Bp, g1b, Pp, denp, rsp);
    k_rowfix<<<Nn, 256, 0, stream>>>(Pp, denp, rsp, Pk, Wl, kc, lg);
    k_gemm2<<<dim3(32, 16), 256, 0, stream>>>(A, lg, part);
    k_reduce<<<512, 256, 0, stream>>>(part, out);
}